// Round 2
// baseline (360.388 us; speedup 1.0000x reference)
//
#include <hip/hip_runtime.h>
#include <stdint.h>

#define B_    16
#define FIN   256
#define FOUT  256
#define FH2   256
#define NMIX  8
#define LAT   512
#define HW    4096
#define MT    32

typedef short bf16x8 __attribute__((ext_vector_type(8)));
typedef float f32x4  __attribute__((ext_vector_type(4)));

// workspace layout (bytes)
#define WS_MIX    0           // [16][8] f32
#define WS_BIAS   1024        // [4][16][256] f32 : in, mid, out, short
#define WS_WIN    131072      // [16][256][256] bf16
#define WS_WMID   2228224     // [16][256][512] bf16 (sin/cos interleaved k')
#define WS_WOUT   6422528     // [16][256][512] bf16 (interleaved)
#define WS_WSHORT 10616832    // [16][256][256] bf16

__device__ __forceinline__ uint16_t f2bf(float f) {
  uint32_t u = __builtin_bit_cast(uint32_t, f);
  u += 0x7fffu + ((u >> 16) & 1u);
  return (uint16_t)(u >> 16);
}
__device__ __forceinline__ uint32_t pack2(float lo, float hi) {
  return (uint32_t)f2bf(lo) | ((uint32_t)f2bf(hi) << 16);
}

#define MFMA(a, b, c) __builtin_amdgcn_mfma_f32_16x16x32_bf16(a, b, c, 0, 0, 0)

// ---------------- kernel A: mix + biases ----------------
__global__ void k_mix_bias(const float* __restrict__ lat,
                           const float* __restrict__ w_dyna,
                           const float* __restrict__ b_dyna,
                           const float* __restrict__ b_in_mix,
                           const float* __restrict__ b_mid_mix,
                           const float* __restrict__ b_out_mix,
                           const float* __restrict__ b_short_mix,
                           float* __restrict__ ws_mix,
                           float* __restrict__ ws_bias) {
  __shared__ float smix[B_ * NMIX];
  const int t = threadIdx.x;
  const int lane = t & 63, wv = t >> 6;
  for (int d2 = 0; d2 < 32; d2++) {
    int d = wv * 32 + d2;
    int b = d >> 3, m = d & 7;
    float s = 0.f;
#pragma unroll
    for (int j = 0; j < 8; j++)
      s += lat[b * LAT + j * 64 + lane] * w_dyna[m * LAT + j * 64 + lane];
#pragma unroll
    for (int off = 32; off; off >>= 1) s += __shfl_xor(s, off);
    if (lane == 0) {
      float v = s + b_dyna[m];
      ws_mix[d] = v;
      smix[d] = v;
    }
  }
  __syncthreads();
  const float* banks[4] = {b_in_mix, b_mid_mix, b_out_mix, b_short_mix};
  for (int pos = t; pos < 1024; pos += 256) {
    int bank = pos >> 8, ch = pos & 255;
    const float* bp = banks[bank];
    float v[NMIX];
#pragma unroll
    for (int m = 0; m < NMIX; m++) v[m] = bp[m * 256 + ch];
#pragma unroll
    for (int b = 0; b < B_; b++) {
      float a = 0.f;
#pragma unroll
      for (int m = 0; m < NMIX; m++) a += smix[b * NMIX + m] * v[m];
      ws_bias[(bank * B_ + b) * 256 + ch] = a;
    }
  }
}

// ---------------- kernel B: mixed per-sample bf16 weights ----------------
__global__ void k_weights(const float* __restrict__ k_in_mix,
                          const float* __restrict__ k_mid_mix,
                          const float* __restrict__ k_out_mix,
                          const float* __restrict__ k_short_mix,
                          const float* __restrict__ ws_mix,
                          uint16_t* __restrict__ w_in,
                          uint16_t* __restrict__ w_mid,
                          uint16_t* __restrict__ w_out,
                          uint16_t* __restrict__ w_short) {
  __shared__ float smix[B_ * NMIX];
  const int t = threadIdx.x;
  if (t < B_ * NMIX) smix[t] = ws_mix[t];
  __syncthreads();
  const int idx = blockIdx.x * 256 + t;  // 0..393215
  const float* src;
  uint16_t* dst;
  int sstride, dstride;
  if (idx < 65536) {
    src = k_in_mix + idx; sstride = 65536;
    dst = w_in + idx;     dstride = 65536;
  } else if (idx < 196608) {
    int j = idx - 65536, o = j >> 9, kp = j & 511;
    int i = (kp >> 1) + ((kp & 1) << 8);      // interleaved sin/cos -> source channel
    src = k_mid_mix + o * 512 + i; sstride = 131072;
    dst = w_mid + j;               dstride = 131072;
  } else if (idx < 327680) {
    int j = idx - 196608, o = j >> 9, kp = j & 511;
    int i = (kp >> 1) + ((kp & 1) << 8);
    src = k_out_mix + o * 512 + i; sstride = 131072;
    dst = w_out + j;               dstride = 131072;
  } else {
    int j = idx - 327680;
    src = k_short_mix + j; sstride = 65536;
    dst = w_short + j;     dstride = 65536;
  }
  float v[NMIX];
#pragma unroll
  for (int m = 0; m < NMIX; m++) v[m] = src[m * sstride];
  for (int b = 0; b < B_; b++) {
    float a = 0.f;
#pragma unroll
    for (int m = 0; m < NMIX; m++) a += smix[b * NMIX + m] * v[m];
    dst[b * dstride] = f2bf(a);
  }
}

// ---------------- main fused kernel ----------------
// Grid: 2048 1-D blocks. b = blk & 15 so XCD r (= blk % 8) touches only samples
// {r, r+8}: 1.5 MB of bf16 weights — resident in that XCD's 4 MB L2.
// block = 256 thr (4 waves), MT=32 spatial cols.
// LDS 48KB -> 3 blocks/CU (12 waves/CU):
//   Xb  @0      16KB  32 rows x 512B, chunk-xor swizzle (c ^ (p&7))
//   H1c @16384  32KB  32 rows x 1024B, chunk-xor swizzle
//   H2c @0      32KB  (overwrites Xb + low half of H1c after stage-2 barrier)
// Weights read straight from L2 with explicit register double-buffering
// (prefetch kt+1 fragments while MFMAing kt) for deep MLP.
__launch_bounds__(256, 3)
__global__ void k_main(const float* __restrict__ x,
                       const float* __restrict__ ws_bias,
                       const uint16_t* __restrict__ w_in,
                       const uint16_t* __restrict__ w_mid,
                       const uint16_t* __restrict__ w_out,
                       const uint16_t* __restrict__ w_short,
                       float* __restrict__ out) {
  __shared__ int4 smem4[49152 / 16];
  char* lds = (char*)smem4;
  char* Xb = lds;
  char* H1 = lds + 16384;
  char* H2 = lds;

  const int t = threadIdx.x;
  const int lane = t & 63;
  const int wv = t >> 6;
  const int q = lane >> 4;
  const int n = lane & 15;
  const int b = blockIdx.x & 15;
  const int p0 = (blockIdx.x >> 4) * MT;

  // ---- stage X tile -> Xb (bf16, swizzled) ----
  {
    const float* xb = x + (size_t)b * FIN * HW + p0;
    const int p = t & 31;
    const int cg = t >> 5;  // 0..7
#pragma unroll
    for (int cc = 0; cc < 4; cc++) {
      int c = cg * 4 + cc;
      float v[8];
#pragma unroll
      for (int e = 0; e < 8; e++) v[e] = xb[(size_t)(c * 8 + e) * HW + p];
      int4 pkt = make_int4((int)pack2(v[0], v[1]), (int)pack2(v[2], v[3]),
                           (int)pack2(v[4], v[5]), (int)pack2(v[6], v[7]));
      *(int4*)(Xb + p * 512 + ((c ^ (p & 7)) * 16)) = pkt;
    }
  }
  __syncthreads();

  // ---- stage 1: h1 = K_in @ X + b_in ; short = K_short @ X + b_short ----
  f32x4 acc_h[4][2], acc_s[4][2];
#pragma unroll
  for (int ots = 0; ots < 4; ots++) {
    int o = wv * 64 + ots * 16 + q * 4;
    float4 vi = *(const float4*)&ws_bias[(0 * B_ + b) * 256 + o];
    float4 vs = *(const float4*)&ws_bias[(3 * B_ + b) * 256 + o];
    acc_h[ots][0][0] = vi.x; acc_h[ots][0][1] = vi.y; acc_h[ots][0][2] = vi.z; acc_h[ots][0][3] = vi.w;
    acc_h[ots][1] = acc_h[ots][0];
    acc_s[ots][0][0] = vs.x; acc_s[ots][0][1] = vs.y; acc_s[ots][0][2] = vs.z; acc_s[ots][0][3] = vs.w;
    acc_s[ots][1] = acc_s[ots][0];
  }
  {
    const uint16_t* Wi = w_in + (size_t)b * 65536;
    const uint16_t* Ws = w_short + (size_t)b * 65536;
    int ro[4];
#pragma unroll
    for (int ots = 0; ots < 4; ots++)
      ro[ots] = (wv * 64 + ots * 16 + n) * 256 + q * 8;
    bf16x8 wi[2][4], wsr[2][4];
#pragma unroll
    for (int ots = 0; ots < 4; ots++) {
      wi[0][ots] = *(const bf16x8*)(Wi + ro[ots]);
      wsr[0][ots] = *(const bf16x8*)(Ws + ro[ots]);
    }
#pragma unroll
    for (int kt = 0; kt < 8; kt++) {
      const int cur = kt & 1, nxt = cur ^ 1;
      if (kt < 7) {
#pragma unroll
        for (int ots = 0; ots < 4; ots++) {
          wi[nxt][ots] = *(const bf16x8*)(Wi + ro[ots] + (kt + 1) * 32);
          wsr[nxt][ots] = *(const bf16x8*)(Ws + ro[ots] + (kt + 1) * 32);
        }
      }
      int sw = ((kt * 4 + q) ^ (n & 7)) * 16;
      bf16x8 bf0 = *(const bf16x8*)(Xb + n * 512 + sw);
      bf16x8 bf1 = *(const bf16x8*)(Xb + (16 + n) * 512 + sw);
#pragma unroll
      for (int ots = 0; ots < 4; ots++) {
        acc_h[ots][0] = MFMA(wi[cur][ots], bf0, acc_h[ots][0]);
        acc_h[ots][1] = MFMA(wi[cur][ots], bf1, acc_h[ots][1]);
        acc_s[ots][0] = MFMA(wsr[cur][ots], bf0, acc_s[ots][0]);
        acc_s[ots][1] = MFMA(wsr[cur][ots], bf1, acc_s[ots][1]);
      }
    }
  }
  // complex_wave(h1) -> H1c, k' = 2*o + {0:sin,1:cos}, chunk-xor swizzle
#pragma unroll
  for (int ots = 0; ots < 4; ots++) {
    int ctile = (wv * 4 + ots) * 4 + q;
#pragma unroll
    for (int pt = 0; pt < 2; pt++) {
      int p = pt * 16 + n;
      uint32_t u0 = pack2(__sinf(acc_h[ots][pt][0]), __cosf(acc_h[ots][pt][0]));
      uint32_t u1 = pack2(__sinf(acc_h[ots][pt][1]), __cosf(acc_h[ots][pt][1]));
      uint32_t u2 = pack2(__sinf(acc_h[ots][pt][2]), __cosf(acc_h[ots][pt][2]));
      uint32_t u3 = pack2(__sinf(acc_h[ots][pt][3]), __cosf(acc_h[ots][pt][3]));
      *(int4*)(H1 + p * 1024 + ((ctile ^ (p & 7)) * 16)) =
          make_int4((int)u0, (int)u1, (int)u2, (int)u3);
    }
  }
  __syncthreads();

  // ---- stage 2: h2 = K_mid(perm) @ H1c + b_mid ----
  f32x4 acc2[4][2];
#pragma unroll
  for (int ots = 0; ots < 4; ots++) {
    int o = wv * 64 + ots * 16 + q * 4;
    float4 v = *(const float4*)&ws_bias[(1 * B_ + b) * 256 + o];
    acc2[ots][0][0] = v.x; acc2[ots][0][1] = v.y; acc2[ots][0][2] = v.z; acc2[ots][0][3] = v.w;
    acc2[ots][1] = acc2[ots][0];
  }
  {
    const uint16_t* Wm = w_mid + (size_t)b * 131072;
    int ro[4];
#pragma unroll
    for (int ots = 0; ots < 4; ots++)
      ro[ots] = (wv * 64 + ots * 16 + n) * 512 + q * 8;
    bf16x8 wm[2][4];
#pragma unroll
    for (int ots = 0; ots < 4; ots++)
      wm[0][ots] = *(const bf16x8*)(Wm + ro[ots]);
#pragma unroll
    for (int kt = 0; kt < 16; kt++) {
      const int cur = kt & 1, nxt = cur ^ 1;
      if (kt < 15) {
#pragma unroll
        for (int ots = 0; ots < 4; ots++)
          wm[nxt][ots] = *(const bf16x8*)(Wm + ro[ots] + (kt + 1) * 32);
      }
      int sw = ((kt * 4 + q) ^ (n & 7)) * 16;
      bf16x8 bf0 = *(const bf16x8*)(H1 + n * 1024 + sw);
      bf16x8 bf1 = *(const bf16x8*)(H1 + (16 + n) * 1024 + sw);
#pragma unroll
      for (int ots = 0; ots < 4; ots++) {
        acc2[ots][0] = MFMA(wm[cur][ots], bf0, acc2[ots][0]);
        acc2[ots][1] = MFMA(wm[cur][ots], bf1, acc2[ots][1]);
      }
    }
  }
  __syncthreads();  // all stage-2 reads of H1/Xb done before H2 overwrite
  // complex_wave(h2) -> H2c
#pragma unroll
  for (int ots = 0; ots < 4; ots++) {
    int ctile = (wv * 4 + ots) * 4 + q;
#pragma unroll
    for (int pt = 0; pt < 2; pt++) {
      int p = pt * 16 + n;
      uint32_t u0 = pack2(__sinf(acc2[ots][pt][0]), __cosf(acc2[ots][pt][0]));
      uint32_t u1 = pack2(__sinf(acc2[ots][pt][1]), __cosf(acc2[ots][pt][1]));
      uint32_t u2 = pack2(__sinf(acc2[ots][pt][2]), __cosf(acc2[ots][pt][2]));
      uint32_t u3 = pack2(__sinf(acc2[ots][pt][3]), __cosf(acc2[ots][pt][3]));
      *(int4*)(H2 + p * 1024 + ((ctile ^ (p & 7)) * 16)) =
          make_int4((int)u0, (int)u1, (int)u2, (int)u3);
    }
  }
  __syncthreads();

  // ---- stage 3: out = K_out(perm) @ H2c + b_out + short ----
  f32x4 acc3[4][2];
#pragma unroll
  for (int ots = 0; ots < 4; ots++) {
    int o = wv * 64 + ots * 16 + q * 4;
    float4 v = *(const float4*)&ws_bias[(2 * B_ + b) * 256 + o];
    acc3[ots][0][0] = acc_s[ots][0][0] + v.x; acc3[ots][0][1] = acc_s[ots][0][1] + v.y;
    acc3[ots][0][2] = acc_s[ots][0][2] + v.z; acc3[ots][0][3] = acc_s[ots][0][3] + v.w;
    acc3[ots][1][0] = acc_s[ots][1][0] + v.x; acc3[ots][1][1] = acc_s[ots][1][1] + v.y;
    acc3[ots][1][2] = acc_s[ots][1][2] + v.z; acc3[ots][1][3] = acc_s[ots][1][3] + v.w;
  }
  {
    const uint16_t* Wo = w_out + (size_t)b * 131072;
    int ro[4];
#pragma unroll
    for (int ots = 0; ots < 4; ots++)
      ro[ots] = (wv * 64 + ots * 16 + n) * 512 + q * 8;
    bf16x8 wo[2][4];
#pragma unroll
    for (int ots = 0; ots < 4; ots++)
      wo[0][ots] = *(const bf16x8*)(Wo + ro[ots]);
#pragma unroll
    for (int kt = 0; kt < 16; kt++) {
      const int cur = kt & 1, nxt = cur ^ 1;
      if (kt < 15) {
#pragma unroll
        for (int ots = 0; ots < 4; ots++)
          wo[nxt][ots] = *(const bf16x8*)(Wo + ro[ots] + (kt + 1) * 32);
      }
      int sw = ((kt * 4 + q) ^ (n & 7)) * 16;
      bf16x8 bf0 = *(const bf16x8*)(H2 + n * 1024 + sw);
      bf16x8 bf1 = *(const bf16x8*)(H2 + (16 + n) * 1024 + sw);
#pragma unroll
      for (int ots = 0; ots < 4; ots++) {
        acc3[ots][0] = MFMA(wo[cur][ots], bf0, acc3[ots][0]);
        acc3[ots][1] = MFMA(wo[cur][ots], bf1, acc3[ots][1]);
      }
    }
  }
  // store
  {
    float* ob = out + (size_t)b * FOUT * HW + p0;
#pragma unroll
    for (int ots = 0; ots < 4; ots++) {
#pragma unroll
      for (int pt = 0; pt < 2; pt++) {
#pragma unroll
        for (int r = 0; r < 4; r++) {
          int o = wv * 64 + ots * 16 + q * 4 + r;
          ob[(size_t)o * HW + pt * 16 + n] = acc3[ots][pt][r];
        }
      }
    }
  }
}

extern "C" void kernel_launch(void* const* d_in, const int* in_sizes, int n_in,
                              void* d_out, int out_size, void* d_ws, size_t ws_size,
                              hipStream_t stream) {
  const float* x           = (const float*)d_in[0];
  const float* lat         = (const float*)d_in[1];
  const float* k_in_mix    = (const float*)d_in[2];
  const float* k_mid_mix   = (const float*)d_in[3];
  const float* k_out_mix   = (const float*)d_in[4];
  const float* k_short_mix = (const float*)d_in[5];
  const float* b_in_mix    = (const float*)d_in[6];
  const float* b_mid_mix   = (const float*)d_in[7];
  const float* b_out_mix   = (const float*)d_in[8];
  const float* b_short_mix = (const float*)d_in[9];
  const float* w_dyna      = (const float*)d_in[10];
  const float* b_dyna      = (const float*)d_in[11];

  char* ws = (char*)d_ws;
  float*    ws_mix  = (float*)(ws + WS_MIX);
  float*    ws_bias = (float*)(ws + WS_BIAS);
  uint16_t* w_in    = (uint16_t*)(ws + WS_WIN);
  uint16_t* w_mid   = (uint16_t*)(ws + WS_WMID);
  uint16_t* w_out   = (uint16_t*)(ws + WS_WOUT);
  uint16_t* w_short = (uint16_t*)(ws + WS_WSHORT);
  float* out = (float*)d_out;

  hipLaunchKernelGGL(k_mix_bias, dim3(1), dim3(256), 0, stream,
                     lat, w_dyna, b_dyna, b_in_mix, b_mid_mix, b_out_mix,
                     b_short_mix, ws_mix, ws_bias);
  hipLaunchKernelGGL(k_weights, dim3(1536), dim3(256), 0, stream,
                     k_in_mix, k_mid_mix, k_out_mix, k_short_mix, ws_mix,
                     w_in, w_mid, w_out, w_short);
  hipLaunchKernelGGL(k_main, dim3(2048), dim3(256), 0, stream,
                     x, ws_bias, w_in, w_mid, w_out, w_short, out);
}

// Round 3
// 234.075 us; speedup vs baseline: 1.5396x; 1.5396x over previous
//
#include <hip/hip_runtime.h>
#include <stdint.h>

#define B_    16
#define FIN   256
#define FOUT  256
#define FH2   256
#define NMIX  8
#define LAT   512
#define HW    4096
#define MT    32

typedef short bf16x8 __attribute__((ext_vector_type(8)));
typedef float f32x4  __attribute__((ext_vector_type(4)));

// workspace layout (bytes)
#define WS_MIX    0           // [16][8] f32
#define WS_BIAS   1024        // [4][16][256] f32 : in, mid, out, short
#define WS_WIN    131072      // [16][65536] bf16, fragment-packed
#define WS_WMID   2228224     // [16][131072] bf16, fragment-packed (sin/cos interleaved k')
#define WS_WOUT   6422528     // [16][131072] bf16, fragment-packed
#define WS_WSHORT 10616832    // [16][65536] bf16, fragment-packed

__device__ __forceinline__ uint16_t f2bf(float f) {
  uint32_t u = __builtin_bit_cast(uint32_t, f);
  u += 0x7fffu + ((u >> 16) & 1u);
  return (uint16_t)(u >> 16);
}
__device__ __forceinline__ uint32_t pack2(float lo, float hi) {
  return (uint32_t)f2bf(lo) | ((uint32_t)f2bf(hi) << 16);
}

#define MFMA(a, b, c) __builtin_amdgcn_mfma_f32_16x16x32_bf16(a, b, c, 0, 0, 0)

// ---------------- kernel A: mix + biases (one block per sample) ----------------
__global__ void k_mix_bias(const float* __restrict__ lat,
                           const float* __restrict__ w_dyna,
                           const float* __restrict__ b_dyna,
                           const float* __restrict__ b_in_mix,
                           const float* __restrict__ b_mid_mix,
                           const float* __restrict__ b_out_mix,
                           const float* __restrict__ b_short_mix,
                           float* __restrict__ ws_mix,
                           float* __restrict__ ws_bias) {
  __shared__ float smix[NMIX];
  const int t = threadIdx.x;
  const int lane = t & 63, wv = t >> 6;
  const int b = blockIdx.x;
#pragma unroll
  for (int d2 = 0; d2 < 2; d2++) {
    int m = wv * 2 + d2;
    float s = 0.f;
#pragma unroll
    for (int j = 0; j < 8; j++)
      s += lat[b * LAT + j * 64 + lane] * w_dyna[m * LAT + j * 64 + lane];
#pragma unroll
    for (int off = 32; off; off >>= 1) s += __shfl_xor(s, off);
    if (lane == 0) {
      float v = s + b_dyna[m];
      ws_mix[b * NMIX + m] = v;
      smix[m] = v;
    }
  }
  __syncthreads();
  const float* banks[4] = {b_in_mix, b_mid_mix, b_out_mix, b_short_mix};
  for (int pos = t; pos < 1024; pos += 256) {
    int bank = pos >> 8, ch = pos & 255;
    const float* bp = banks[bank];
    float a = 0.f;
#pragma unroll
    for (int m = 0; m < NMIX; m++) a += smix[m] * bp[m * 256 + ch];
    ws_bias[(bank * B_ + b) * 256 + ch] = a;
  }
}

// ---------------- kernel B: mixed per-sample bf16 weights, FRAGMENT-PACKED ----
// Packed element order (per sample, per matrix):
//   e = ((wv*KT + kt)*4 + ots)*512 + lane*8 + j
// holding W[row = wv*64 + ots*16 + (lane&15)][k = kt*32 + (lane>>4)*8 + j]
// so k_main's A-fragment load at (wv,kt,ots) is lane-contiguous (dense 1KB).
__global__ void k_weights(const float* __restrict__ k_in_mix,
                          const float* __restrict__ k_mid_mix,
                          const float* __restrict__ k_out_mix,
                          const float* __restrict__ k_short_mix,
                          const float* __restrict__ ws_mix,
                          uint16_t* __restrict__ w_in,
                          uint16_t* __restrict__ w_mid,
                          uint16_t* __restrict__ w_out,
                          uint16_t* __restrict__ w_short) {
  __shared__ float smix[B_ * NMIX];
  const int t = threadIdx.x;
  if (t < B_ * NMIX) smix[t] = ws_mix[t];
  __syncthreads();
  const int idx = blockIdx.x * 256 + t;  // 0..393215 packed positions
  const float* src;
  uint16_t* dst;
  int sstride, dstride;
  if (idx < 65536) {                      // w_in, KT=8
    int e = idx;
    int j = e & 7, lane = (e >> 3) & 63, ots = (e >> 9) & 3, kt = (e >> 11) & 7, wv = e >> 14;
    int row = wv * 64 + ots * 16 + (lane & 15);
    int k = kt * 32 + (lane >> 4) * 8 + j;
    src = k_in_mix + row * 256 + k; sstride = 65536;
    dst = w_in + e;                 dstride = 65536;
  } else if (idx < 196608) {              // w_mid, KT=16, sin/cos interleave
    int e = idx - 65536;
    int j = e & 7, lane = (e >> 3) & 63, ots = (e >> 9) & 3, kt = (e >> 11) & 15, wv = e >> 15;
    int row = wv * 64 + ots * 16 + (lane & 15);
    int kp = kt * 32 + (lane >> 4) * 8 + j;
    int i = (kp >> 1) + ((kp & 1) << 8);
    src = k_mid_mix + row * 512 + i; sstride = 131072;
    dst = w_mid + e;                 dstride = 131072;
  } else if (idx < 327680) {              // w_out, KT=16, interleave
    int e = idx - 196608;
    int j = e & 7, lane = (e >> 3) & 63, ots = (e >> 9) & 3, kt = (e >> 11) & 15, wv = e >> 15;
    int row = wv * 64 + ots * 16 + (lane & 15);
    int kp = kt * 32 + (lane >> 4) * 8 + j;
    int i = (kp >> 1) + ((kp & 1) << 8);
    src = k_out_mix + row * 512 + i; sstride = 131072;
    dst = w_out + e;                 dstride = 131072;
  } else {                                // w_short, KT=8
    int e = idx - 327680;
    int j = e & 7, lane = (e >> 3) & 63, ots = (e >> 9) & 3, kt = (e >> 11) & 7, wv = e >> 14;
    int row = wv * 64 + ots * 16 + (lane & 15);
    int k = kt * 32 + (lane >> 4) * 8 + j;
    src = k_short_mix + row * 256 + k; sstride = 65536;
    dst = w_short + e;                 dstride = 65536;
  }
  float v[NMIX];
#pragma unroll
  for (int m = 0; m < NMIX; m++) v[m] = src[m * sstride];
  for (int b = 0; b < B_; b++) {
    float a = 0.f;
#pragma unroll
    for (int m = 0; m < NMIX; m++) a += smix[b * NMIX + m] * v[m];
    dst[b * dstride] = f2bf(a);
  }
}

// ---------------- main fused kernel ----------------
// Grid: 2048 blocks, b = blk & 15 (XCD r holds samples {r, r+8} in its L2).
// Weights are fragment-packed: every weight load = dense coalesced 1KB.
// LDS 48KB -> 3 blocks/CU:
//   Xb @0 (16KB), H1 @16384 (32KB), H2 @0 (32KB, after stage-2 barrier).
__launch_bounds__(256, 3)
__global__ void k_main(const float* __restrict__ x,
                       const float* __restrict__ ws_bias,
                       const uint16_t* __restrict__ w_in,
                       const uint16_t* __restrict__ w_mid,
                       const uint16_t* __restrict__ w_out,
                       const uint16_t* __restrict__ w_short,
                       float* __restrict__ out) {
  __shared__ int4 smem4[49152 / 16];
  char* lds = (char*)smem4;
  char* Xb = lds;
  char* H1 = lds + 16384;
  char* H2 = lds;

  const int t = threadIdx.x;
  const int lane = t & 63;
  const int wv = t >> 6;
  const int q = lane >> 4;
  const int n = lane & 15;
  const int b = blockIdx.x & 15;
  const int p0 = (blockIdx.x >> 4) * MT;

  // ---- stage X tile -> Xb (bf16, chunk-xor swizzled) ----
  {
    const float* xb = x + (size_t)b * FIN * HW + p0;
    const int p = t & 31;
    const int cg = t >> 5;  // 0..7
#pragma unroll
    for (int cc = 0; cc < 4; cc++) {
      int c = cg * 4 + cc;
      float v[8];
#pragma unroll
      for (int e = 0; e < 8; e++) v[e] = xb[(size_t)(c * 8 + e) * HW + p];
      int4 pkt = make_int4((int)pack2(v[0], v[1]), (int)pack2(v[2], v[3]),
                           (int)pack2(v[4], v[5]), (int)pack2(v[6], v[7]));
      *(int4*)(Xb + p * 512 + ((c ^ (p & 7)) * 16)) = pkt;
    }
  }
  __syncthreads();

  // ---- stage 1: h1 = K_in @ X + b_in ; short = K_short @ X + b_short ----
  f32x4 acc_h[4][2], acc_s[4][2];
#pragma unroll
  for (int ots = 0; ots < 4; ots++) {
    int o = wv * 64 + ots * 16 + q * 4;
    float4 vi = *(const float4*)&ws_bias[(0 * B_ + b) * 256 + o];
    float4 vs = *(const float4*)&ws_bias[(3 * B_ + b) * 256 + o];
    acc_h[ots][0][0] = vi.x; acc_h[ots][0][1] = vi.y; acc_h[ots][0][2] = vi.z; acc_h[ots][0][3] = vi.w;
    acc_h[ots][1] = acc_h[ots][0];
    acc_s[ots][0][0] = vs.x; acc_s[ots][0][1] = vs.y; acc_s[ots][0][2] = vs.z; acc_s[ots][0][3] = vs.w;
    acc_s[ots][1] = acc_s[ots][0];
  }
  {
    const uint16_t* Wi = w_in + (size_t)b * 65536 + wv * 16384 + lane * 8;
    const uint16_t* Ws = w_short + (size_t)b * 65536 + wv * 16384 + lane * 8;
#pragma unroll
    for (int kt = 0; kt < 8; kt++) {
      int sw = ((kt * 4 + q) ^ (n & 7)) * 16;
      bf16x8 bf0 = *(const bf16x8*)(Xb + n * 512 + sw);
      bf16x8 bf1 = *(const bf16x8*)(Xb + (16 + n) * 512 + sw);
#pragma unroll
      for (int ots = 0; ots < 4; ots++) {
        bf16x8 ai = *(const bf16x8*)(Wi + kt * 2048 + ots * 512);
        bf16x8 as = *(const bf16x8*)(Ws + kt * 2048 + ots * 512);
        acc_h[ots][0] = MFMA(ai, bf0, acc_h[ots][0]);
        acc_h[ots][1] = MFMA(ai, bf1, acc_h[ots][1]);
        acc_s[ots][0] = MFMA(as, bf0, acc_s[ots][0]);
        acc_s[ots][1] = MFMA(as, bf1, acc_s[ots][1]);
      }
    }
  }
  // complex_wave(h1) -> H1c, k' = 2*o + {0:sin,1:cos}, chunk-xor swizzle
#pragma unroll
  for (int ots = 0; ots < 4; ots++) {
    int ctile = (wv * 4 + ots) * 4 + q;
#pragma unroll
    for (int pt = 0; pt < 2; pt++) {
      int p = pt * 16 + n;
      uint32_t u0 = pack2(__sinf(acc_h[ots][pt][0]), __cosf(acc_h[ots][pt][0]));
      uint32_t u1 = pack2(__sinf(acc_h[ots][pt][1]), __cosf(acc_h[ots][pt][1]));
      uint32_t u2 = pack2(__sinf(acc_h[ots][pt][2]), __cosf(acc_h[ots][pt][2]));
      uint32_t u3 = pack2(__sinf(acc_h[ots][pt][3]), __cosf(acc_h[ots][pt][3]));
      *(int4*)(H1 + p * 1024 + ((ctile ^ (p & 7)) * 16)) =
          make_int4((int)u0, (int)u1, (int)u2, (int)u3);
    }
  }
  __syncthreads();

  // ---- stage 2: h2 = K_mid(perm) @ H1c + b_mid ----
  f32x4 acc2[4][2];
#pragma unroll
  for (int ots = 0; ots < 4; ots++) {
    int o = wv * 64 + ots * 16 + q * 4;
    float4 v = *(const float4*)&ws_bias[(1 * B_ + b) * 256 + o];
    acc2[ots][0][0] = v.x; acc2[ots][0][1] = v.y; acc2[ots][0][2] = v.z; acc2[ots][0][3] = v.w;
    acc2[ots][1] = acc2[ots][0];
  }
  {
    const uint16_t* Wm = w_mid + (size_t)b * 131072 + wv * 32768 + lane * 8;
#pragma unroll
    for (int kt = 0; kt < 16; kt++) {
      int sw = ((kt * 4 + q) ^ (n & 7)) * 16;
      bf16x8 bf0 = *(const bf16x8*)(H1 + n * 1024 + sw);
      bf16x8 bf1 = *(const bf16x8*)(H1 + (16 + n) * 1024 + sw);
#pragma unroll
      for (int ots = 0; ots < 4; ots++) {
        bf16x8 am = *(const bf16x8*)(Wm + kt * 2048 + ots * 512);
        acc2[ots][0] = MFMA(am, bf0, acc2[ots][0]);
        acc2[ots][1] = MFMA(am, bf1, acc2[ots][1]);
      }
    }
  }
  __syncthreads();  // all stage-2 reads of H1/Xb done before H2 overwrite
  // complex_wave(h2) -> H2c
#pragma unroll
  for (int ots = 0; ots < 4; ots++) {
    int ctile = (wv * 4 + ots) * 4 + q;
#pragma unroll
    for (int pt = 0; pt < 2; pt++) {
      int p = pt * 16 + n;
      uint32_t u0 = pack2(__sinf(acc2[ots][pt][0]), __cosf(acc2[ots][pt][0]));
      uint32_t u1 = pack2(__sinf(acc2[ots][pt][1]), __cosf(acc2[ots][pt][1]));
      uint32_t u2 = pack2(__sinf(acc2[ots][pt][2]), __cosf(acc2[ots][pt][2]));
      uint32_t u3 = pack2(__sinf(acc2[ots][pt][3]), __cosf(acc2[ots][pt][3]));
      *(int4*)(H2 + p * 1024 + ((ctile ^ (p & 7)) * 16)) =
          make_int4((int)u0, (int)u1, (int)u2, (int)u3);
    }
  }
  __syncthreads();

  // ---- stage 3: out = K_out(perm) @ H2c + b_out + short ----
  f32x4 acc3[4][2];
#pragma unroll
  for (int ots = 0; ots < 4; ots++) {
    int o = wv * 64 + ots * 16 + q * 4;
    float4 v = *(const float4*)&ws_bias[(2 * B_ + b) * 256 + o];
    acc3[ots][0][0] = acc_s[ots][0][0] + v.x; acc3[ots][0][1] = acc_s[ots][0][1] + v.y;
    acc3[ots][0][2] = acc_s[ots][0][2] + v.z; acc3[ots][0][3] = acc_s[ots][0][3] + v.w;
    acc3[ots][1][0] = acc_s[ots][1][0] + v.x; acc3[ots][1][1] = acc_s[ots][1][1] + v.y;
    acc3[ots][1][2] = acc_s[ots][1][2] + v.z; acc3[ots][1][3] = acc_s[ots][1][3] + v.w;
  }
  {
    const uint16_t* Wo = w_out + (size_t)b * 131072 + wv * 32768 + lane * 8;
#pragma unroll
    for (int kt = 0; kt < 16; kt++) {
      int sw = ((kt * 4 + q) ^ (n & 7)) * 16;
      bf16x8 bf0 = *(const bf16x8*)(H2 + n * 1024 + sw);
      bf16x8 bf1 = *(const bf16x8*)(H2 + (16 + n) * 1024 + sw);
#pragma unroll
      for (int ots = 0; ots < 4; ots++) {
        bf16x8 ao = *(const bf16x8*)(Wo + kt * 2048 + ots * 512);
        acc3[ots][0] = MFMA(ao, bf0, acc3[ots][0]);
        acc3[ots][1] = MFMA(ao, bf1, acc3[ots][1]);
      }
    }
  }
  // store
  {
    float* ob = out + (size_t)b * FOUT * HW + p0;
#pragma unroll
    for (int ots = 0; ots < 4; ots++) {
#pragma unroll
      for (int pt = 0; pt < 2; pt++) {
#pragma unroll
        for (int r = 0; r < 4; r++) {
          int o = wv * 64 + ots * 16 + q * 4 + r;
          ob[(size_t)o * HW + pt * 16 + n] = acc3[ots][pt][r];
        }
      }
    }
  }
}

extern "C" void kernel_launch(void* const* d_in, const int* in_sizes, int n_in,
                              void* d_out, int out_size, void* d_ws, size_t ws_size,
                              hipStream_t stream) {
  const float* x           = (const float*)d_in[0];
  const float* lat         = (const float*)d_in[1];
  const float* k_in_mix    = (const float*)d_in[2];
  const float* k_mid_mix   = (const float*)d_in[3];
  const float* k_out_mix   = (const float*)d_in[4];
  const float* k_short_mix = (const float*)d_in[5];
  const float* b_in_mix    = (const float*)d_in[6];
  const float* b_mid_mix   = (const float*)d_in[7];
  const float* b_out_mix   = (const float*)d_in[8];
  const float* b_short_mix = (const float*)d_in[9];
  const float* w_dyna      = (const float*)d_in[10];
  const float* b_dyna      = (const float*)d_in[11];

  char* ws = (char*)d_ws;
  float*    ws_mix  = (float*)(ws + WS_MIX);
  float*    ws_bias = (float*)(ws + WS_BIAS);
  uint16_t* w_in    = (uint16_t*)(ws + WS_WIN);
  uint16_t* w_mid   = (uint16_t*)(ws + WS_WMID);
  uint16_t* w_out   = (uint16_t*)(ws + WS_WOUT);
  uint16_t* w_short = (uint16_t*)(ws + WS_WSHORT);
  float* out = (float*)d_out;

  hipLaunchKernelGGL(k_mix_bias, dim3(16), dim3(256), 0, stream,
                     lat, w_dyna, b_dyna, b_in_mix, b_mid_mix, b_out_mix,
                     b_short_mix, ws_mix, ws_bias);
  hipLaunchKernelGGL(k_weights, dim3(1536), dim3(256), 0, stream,
                     k_in_mix, k_mid_mix, k_out_mix, k_short_mix, ws_mix,
                     w_in, w_mid, w_out, w_short);
  hipLaunchKernelGGL(k_main, dim3(2048), dim3(256), 0, stream,
                     x, ws_bias, w_in, w_mid, w_out, w_short, out);
}